// Round 4
// baseline (1409.409 us; speedup 1.0000x reference)
//
#include <hip/hip_runtime.h>
#include <math.h>

typedef float f4 __attribute__((ext_vector_type(4)));

#define LOGIT_MAX_F 4.605170185988092f

// ---------------------------------------------------------------- CPB tables
// sbt[row][h] = 16*sigmoid( relu(table_row @ w1 + b1) @ w2 )[h]   (f32)
__global__ __launch_bounds__(64) void k_cpb(const float* __restrict__ w1,
                                            const float* __restrict__ b1,
                                            const float* __restrict__ w2,
                                            float* __restrict__ sbt,
                                            int n_cw, float inv_p0, float inv_p1,
                                            int ts_n0, int ts_n1) {
  int row = blockIdx.x;
  int lane = threadIdx.x;
  int ih = row / n_cw, iw = row % n_cw;
  float v0 = (float)(ts_n0 + ih) * inv_p0 * 8.0f;
  float v1 = (float)(ts_n1 + iw) * inv_p1 * 8.0f;
  v0 = (v0 >= 0.f ? 1.f : -1.f) * log2f(fabsf(v0) + 1.f) * (1.f / 3.f);
  v1 = (v1 >= 0.f ? 1.f : -1.f) * log2f(fabsf(v1) + 1.f) * (1.f / 3.f);
  float a0 = 0.f, a1 = 0.f, a2 = 0.f, a3 = 0.f;
  for (int j = lane; j < 512; j += 64) {
    float h = v0 * w1[j] + v1 * w1[512 + j] + b1[j];
    h = fmaxf(h, 0.f);
    a0 += h * w2[j * 4 + 0];
    a1 += h * w2[j * 4 + 1];
    a2 += h * w2[j * 4 + 2];
    a3 += h * w2[j * 4 + 3];
  }
#pragma unroll
  for (int off = 32; off > 0; off >>= 1) {
    a0 += __shfl_down(a0, off);
    a1 += __shfl_down(a1, off);
    a2 += __shfl_down(a2, off);
    a3 += __shfl_down(a3, off);
  }
  if (lane == 0) {
    sbt[row * 4 + 0] = 16.f / (1.f + expf(-a0));
    sbt[row * 4 + 1] = 16.f / (1.f + expf(-a1));
    sbt[row * 4 + 2] = 16.f / (1.f + expf(-a2));
    sbt[row * 4 + 3] = 16.f / (1.f + expf(-a3));
  }
}

// ---------------------------------------------------------------- 4x4 mean pool
__global__ __launch_bounds__(256) void k_pool(const float* __restrict__ x,
                                              float* __restrict__ pooled) {
  int blk = blockIdx.x;            // (b, gi, gj)
  int c = threadIdx.x;
  int b = blk >> 8, gi = (blk >> 4) & 15, gj = blk & 15;
  const float* xp = x + (size_t)b * 4096 * 256 + c;
  float s = 0.f;
#pragma unroll
  for (int di = 0; di < 4; di++)
#pragma unroll
    for (int dj = 0; dj < 4; dj++)
      s += xp[(size_t)((gi * 4 + di) * 64 + gj * 4 + dj) * 256];
  pooled[(size_t)blk * 256 + c] = s * 0.0625f;
}

// ---------------------------------------------------------------- f32 GEMM
// C[M,N] = A[M,K] @ W[K, ld=ldw, slice n0..] + bias[N];  M%64==0, N%64==0, K%16==0
__global__ __launch_bounds__(256) void k_gemm(const float* __restrict__ A,
                                              const float* __restrict__ W,
                                              const float* __restrict__ bias,
                                              float* __restrict__ C,
                                              int M, int N, int K, int ldw) {
  __shared__ float a_s[16][64];   // [k][m]
  __shared__ float w_s[16][64];   // [k][n]
  const int ntg = N >> 6;
  const int mb = blockIdx.x / ntg, nb = blockIdx.x % ntg;
  const int m0 = mb << 6, n0 = nb << 6;
  const int tid = threadIdx.x;
  const int tx = tid & 15, ty = tid >> 4;
  const int ar = tid >> 2, ac4 = (tid & 3) << 2;
  const int wk = tid >> 4, wc4 = (tid & 15) << 2;
  float acc[4][4] = {};
  for (int k0 = 0; k0 < K; k0 += 16) {
    f4 av = *(const f4*)(A + (size_t)(m0 + ar) * K + k0 + ac4);
    f4 wv = *(const f4*)(W + (size_t)(k0 + wk) * ldw + n0 + wc4);
    __syncthreads();
    a_s[ac4 + 0][ar] = av[0];
    a_s[ac4 + 1][ar] = av[1];
    a_s[ac4 + 2][ar] = av[2];
    a_s[ac4 + 3][ar] = av[3];
    *(f4*)(&w_s[wk][wc4]) = wv;
    __syncthreads();
#pragma unroll
    for (int kk = 0; kk < 16; kk++) {
      f4 a4 = *(const f4*)(&a_s[kk][ty << 2]);
      f4 w4 = *(const f4*)(&w_s[kk][tx << 2]);
#pragma unroll
      for (int i = 0; i < 4; i++)
#pragma unroll
        for (int j = 0; j < 4; j++)
          acc[i][j] = fmaf(a4[i], w4[j], acc[i][j]);
    }
  }
#pragma unroll
  for (int i = 0; i < 4; i++) {
    const int row = m0 + (ty << 2) + i;
#pragma unroll
    for (int j = 0; j < 4; j++) {
      const int col = n0 + (tx << 2) + j;
      C[(size_t)row * N + col] = acc[i][j] + bias[col];
    }
  }
}

// ---------------------------------------------------------------- in-place proj
// io[M,256] = io[M,256] @ W[256,256] + bias; one block = 16 rows (own rows only)
__global__ __launch_bounds__(256) void k_proj(const float* __restrict__ W,
                                              const float* __restrict__ bias,
                                              float* __restrict__ io) {
  __shared__ float a_sT[256][16];  // [k][r]
  const int m0 = blockIdx.x * 16;
  const int tid = threadIdx.x;
  {
    const int r = tid >> 4, cb = (tid & 15) << 4;
#pragma unroll
    for (int i = 0; i < 4; i++) {
      f4 v = *(const f4*)(io + (size_t)(m0 + r) * 256 + cb + i * 4);
      a_sT[cb + i * 4 + 0][r] = v[0];
      a_sT[cb + i * 4 + 1][r] = v[1];
      a_sT[cb + i * 4 + 2][r] = v[2];
      a_sT[cb + i * 4 + 3][r] = v[3];
    }
  }
  __syncthreads();
  const int n = tid;
  f4 acc0 = {0.f, 0.f, 0.f, 0.f}, acc1 = acc0, acc2 = acc0, acc3 = acc0;
#pragma unroll 4
  for (int k = 0; k < 256; k++) {
    const float w = W[(size_t)k * 256 + n];
    f4 a0 = *(const f4*)(&a_sT[k][0]);
    f4 a1 = *(const f4*)(&a_sT[k][4]);
    f4 a2 = *(const f4*)(&a_sT[k][8]);
    f4 a3 = *(const f4*)(&a_sT[k][12]);
    acc0 += a0 * w;
    acc1 += a1 * w;
    acc2 += a2 * w;
    acc3 += a3 * w;
  }
  const float bv = bias[n];
  float accs[16];
#pragma unroll
  for (int i = 0; i < 4; i++) {
    accs[i] = acc0[i]; accs[4 + i] = acc1[i]; accs[8 + i] = acc2[i]; accs[12 + i] = acc3[i];
  }
  __syncthreads();
#pragma unroll
  for (int r = 0; r < 16; r++)
    io[(size_t)(m0 + r) * 256 + n] = accs[r] + bv;
}

// ---------------------------------------------------------------- window attention
// qkvw rows stride 384 (q 0..127, k 128..255, v 256..383), chunk-local
__global__ __launch_bounds__(256) void k_win_attn(const float* __restrict__ qkvw,
                                                  const float* __restrict__ sbt,
                                                  const float* __restrict__ ls,
                                                  float* __restrict__ outp) {
  __shared__ float k_s[256][40];
  __shared__ float kinv[256];
  __shared__ float bias_s[961];
  const int head = blockIdx.x & 3, win = blockIdx.x >> 2;
  const int b = win >> 4, wh = (win >> 2) & 3, ww = win & 3;
  const size_t rowbase = (size_t)b * 4096 + wh * 1024 + ww * 16;
  const int tid = threadIdx.x;
  const float escale = __expf(fminf(ls[head], LOGIT_MAX_F));
  {  // stage K row `tid` + inv-norm
    const float* kp = qkvw + (rowbase + (tid >> 4) * 64 + (tid & 15)) * 384 + 128 + head * 32;
    float ss = 0.f;
#pragma unroll
    for (int c = 0; c < 8; c++) {
      f4 kv = *(const f4*)(kp + c * 4);
      *(f4*)(&k_s[tid][c * 4]) = kv;
      ss += kv[0] * kv[0] + kv[1] * kv[1] + kv[2] * kv[2] + kv[3] * kv[3];
    }
    kinv[tid] = 1.f / fmaxf(sqrtf(ss), 1e-12f);
  }
  for (int i = tid; i < 961; i += 256) bias_s[i] = sbt[i * 4 + head];
  __syncthreads();

  const int qi = tid >> 4, qj = tid & 15;
  const float* qp = qkvw + (rowbase + qi * 64 + qj) * 384 + head * 32;
  f4 q8[8];
  float qss = 0.f;
#pragma unroll
  for (int c = 0; c < 8; c++) {
    q8[c] = *(const f4*)(qp + c * 4);
    qss += q8[c][0] * q8[c][0] + q8[c][1] * q8[c][1] + q8[c][2] * q8[c][2] + q8[c][3] * q8[c][3];
  }
  const float qsc = escale / fmaxf(sqrtf(qss), 1e-12f);

  float mx = -1e30f;
  for (int ki = 0; ki < 16; ki++) {
    const int bbase = (qi - ki + 15) * 31 + qj + 15;
#pragma unroll 1
    for (int kj = 0; kj < 16; kj++) {
      const int key = ki * 16 + kj;
      float s = 0.f;
#pragma unroll
      for (int c = 0; c < 8; c++) {
        f4 kv = *(const f4*)(&k_s[key][c * 4]);
        s = fmaf(q8[c][0], kv[0], s); s = fmaf(q8[c][1], kv[1], s);
        s = fmaf(q8[c][2], kv[2], s); s = fmaf(q8[c][3], kv[3], s);
      }
      s = s * qsc * kinv[key] + bias_s[bbase - kj];
      mx = fmaxf(mx, s);
    }
  }
  f4 o8[8] = {};
  float rs = 0.f;
  for (int ki = 0; ki < 16; ki++) {
    const int bbase = (qi - ki + 15) * 31 + qj + 15;
#pragma unroll 1
    for (int kj = 0; kj < 16; kj++) {
      const int key = ki * 16 + kj;
      float s = 0.f;
#pragma unroll
      for (int c = 0; c < 8; c++) {
        f4 kv = *(const f4*)(&k_s[key][c * 4]);
        s = fmaf(q8[c][0], kv[0], s); s = fmaf(q8[c][1], kv[1], s);
        s = fmaf(q8[c][2], kv[2], s); s = fmaf(q8[c][3], kv[3], s);
      }
      s = s * qsc * kinv[key] + bias_s[bbase - kj];
      const float p = __expf(s - mx);
      rs += p;
      const float* vp = qkvw + (rowbase + ki * 64 + kj) * 384 + 256 + head * 32;
#pragma unroll
      for (int c = 0; c < 8; c++) {
        f4 vv = *(const f4*)(vp + c * 4);
        o8[c] += vv * p;
      }
    }
  }
  const float inv = 1.f / rs;
  float* op = outp + (rowbase + qi * 64 + qj) * 256 + head * 32;
#pragma unroll
  for (int c = 0; c < 8; c++) {
    f4 v = o8[c] * inv;
    *(f4*)(op + c * 4) = v;
  }
}

// ---------------------------------------------------------------- stripe stage 1
// anchors (64 q) attend to 1024 tokens; block=(b,wj,head); 4-way key split
__global__ __launch_bounds__(256) void k_stripe1(const float* __restrict__ qkvs,
                                                 const float* __restrict__ anch,
                                                 const float* __restrict__ sbt,
                                                 const float* __restrict__ ls,
                                                 float* __restrict__ tbuf) {
  __shared__ float ansc[64];
  __shared__ float bias_s[1501];
  __shared__ float red[64][4];
  __shared__ float opart[64][4][33];
  const int head = blockIdx.x & 3, sb = blockIdx.x >> 2;
  const int b = sb >> 2, wj = sb & 3;
  const size_t rowbase = (size_t)b * 4096 + wj * 16;
  const size_t abase = (size_t)b * 256 + wj * 4;
  const int tid = threadIdx.x;
  const int q = tid & 63, sl = tid >> 6;
  const float escale = __expf(fminf(ls[head], LOGIT_MAX_F));
  if (tid < 64) {
    const float* ap = anch + (abase + (tid >> 2) * 16 + (tid & 3)) * 128 + head * 32;
    float ss = 0.f;
#pragma unroll
    for (int c = 0; c < 8; c++) {
      f4 v = *(const f4*)(ap + c * 4);
      ss += v[0] * v[0] + v[1] * v[1] + v[2] * v[2] + v[3] * v[3];
    }
    ansc[tid] = 1.f / fmaxf(sqrtf(ss), 1e-12f);
  }
  for (int i = tid; i < 1501; i += 256) bias_s[i] = sbt[i * 4 + head];
  __syncthreads();

  const float* qp = anch + (abase + (q >> 2) * 16 + (q & 3)) * 128 + head * 32;
  f4 q8[8];
#pragma unroll
  for (int c = 0; c < 8; c++) q8[c] = *(const f4*)(qp + c * 4);
  const float qsc = escale * ansc[q];
  const int ah = q >> 2, aw = q & 3;

  float mx = -1e30f;
#pragma unroll 1
  for (int kt = sl * 256; kt < sl * 256 + 256; kt++) {
    const int ti = kt >> 4, tj = kt & 15;
    const float* kp = qkvs + (rowbase + ti * 64 + tj) * 384 + 128 + head * 32;
    float s = 0.f, kk = 0.f;
#pragma unroll
    for (int c = 0; c < 8; c++) {
      f4 kv = *(const f4*)(kp + c * 4);
      s = fmaf(q8[c][0], kv[0], s); s = fmaf(q8[c][1], kv[1], s);
      s = fmaf(q8[c][2], kv[2], s); s = fmaf(q8[c][3], kv[3], s);
      kk += kv[0] * kv[0] + kv[1] * kv[1] + kv[2] * kv[2] + kv[3] * kv[3];
    }
    s = s * qsc / fmaxf(sqrtf(kk), 1e-12f) + bias_s[(ah - ti + 63) * 19 + (aw - tj + 15)];
    mx = fmaxf(mx, s);
  }
  red[q][sl] = mx;
  __syncthreads();
  mx = fmaxf(fmaxf(red[q][0], red[q][1]), fmaxf(red[q][2], red[q][3]));

  f4 o8[8] = {};
  float rs = 0.f;
#pragma unroll 1
  for (int kt = sl * 256; kt < sl * 256 + 256; kt++) {
    const int ti = kt >> 4, tj = kt & 15;
    const float* kp = qkvs + (rowbase + ti * 64 + tj) * 384 + 128 + head * 32;
    float s = 0.f, kk = 0.f;
#pragma unroll
    for (int c = 0; c < 8; c++) {
      f4 kv = *(const f4*)(kp + c * 4);
      s = fmaf(q8[c][0], kv[0], s); s = fmaf(q8[c][1], kv[1], s);
      s = fmaf(q8[c][2], kv[2], s); s = fmaf(q8[c][3], kv[3], s);
      kk += kv[0] * kv[0] + kv[1] * kv[1] + kv[2] * kv[2] + kv[3] * kv[3];
    }
    s = s * qsc / fmaxf(sqrtf(kk), 1e-12f) + bias_s[(ah - ti + 63) * 19 + (aw - tj + 15)];
    const float p = __expf(s - mx);
    rs += p;
    const float* vp = qkvs + (rowbase + ti * 64 + tj) * 384 + 256 + head * 32;
#pragma unroll
    for (int c = 0; c < 8; c++) {
      f4 vv = *(const f4*)(vp + c * 4);
      o8[c] += vv * p;
    }
  }
  __syncthreads();   // protect red reuse
  red[q][sl] = rs;
#pragma unroll
  for (int c = 0; c < 8; c++) {
    opart[q][sl][c * 4 + 0] = o8[c][0];
    opart[q][sl][c * 4 + 1] = o8[c][1];
    opart[q][sl][c * 4 + 2] = o8[c][2];
    opart[q][sl][c * 4 + 3] = o8[c][3];
  }
  __syncthreads();
  {  // combine: thread -> (q2 = tid>>2, channel-group (tid&3)*8)
    const int q2 = tid >> 2, cg = (tid & 3) << 3;
    const float inv = 1.f / (red[q2][0] + red[q2][1] + red[q2][2] + red[q2][3]);
    float* tp = tbuf + (size_t)blockIdx.x * 2048 + q2 * 32 + cg;
#pragma unroll
    for (int i = 0; i < 8; i++) {
      const int c = cg + i;
      tp[i] = (opart[q2][0][c] + opart[q2][1][c] + opart[q2][2][c] + opart[q2][3][c]) * inv;
    }
  }
}

// ---------------------------------------------------------------- stripe stage 2
// 1024 tokens attend to 64 anchors, values = t
__global__ __launch_bounds__(256) void k_stripe2(const float* __restrict__ qkvs,
                                                 const float* __restrict__ anch,
                                                 const float* __restrict__ tbuf,
                                                 const float* __restrict__ sbt,
                                                 const float* __restrict__ ls,
                                                 float* __restrict__ outp) {
  __shared__ float a_s[64][32];
  __shared__ float t_s[64][32];
  __shared__ float ansc[64];
  __shared__ float bias_s[1501];
  const int head = blockIdx.x & 3, sb = blockIdx.x >> 2;
  const int b = sb >> 2, wj = sb & 3;
  const size_t rowbase = (size_t)b * 4096 + wj * 16;
  const size_t abase = (size_t)b * 256 + wj * 4;
  const int tid = threadIdx.x;
  const float escale = __expf(fminf(ls[head], LOGIT_MAX_F));
  if (tid < 64) {
    const float* ap = anch + (abase + (tid >> 2) * 16 + (tid & 3)) * 128 + head * 32;
    const float* tp = tbuf + (size_t)blockIdx.x * 2048 + tid * 32;
    float ss = 0.f;
#pragma unroll
    for (int c = 0; c < 8; c++) {
      f4 v = *(const f4*)(ap + c * 4);
      *(f4*)(&a_s[tid][c * 4]) = v;
      ss += v[0] * v[0] + v[1] * v[1] + v[2] * v[2] + v[3] * v[3];
      *(f4*)(&t_s[tid][c * 4]) = *(const f4*)(tp + c * 4);
    }
    ansc[tid] = 1.f / fmaxf(sqrtf(ss), 1e-12f);
  }
  for (int i = tid; i < 1501; i += 256) bias_s[i] = sbt[i * 4 + head];
  __syncthreads();

#pragma unroll 1
  for (int rep = 0; rep < 4; rep++) {
    const int qt = rep * 256 + tid;
    const int ti = qt >> 4, tj = qt & 15;
    const float* qp = qkvs + (rowbase + ti * 64 + tj) * 384 + head * 32;
    f4 q8[8];
    float qss = 0.f;
#pragma unroll
    for (int c = 0; c < 8; c++) {
      q8[c] = *(const f4*)(qp + c * 4);
      qss += q8[c][0] * q8[c][0] + q8[c][1] * q8[c][1] + q8[c][2] * q8[c][2] + q8[c][3] * q8[c][3];
    }
    const float qsc = escale / fmaxf(sqrtf(qss), 1e-12f);
    float mx = -1e30f;
#pragma unroll 1
    for (int a = 0; a < 64; a++) {
      float s = 0.f;
#pragma unroll
      for (int c = 0; c < 8; c++) {
        f4 kv = *(const f4*)(&a_s[a][c * 4]);
        s = fmaf(q8[c][0], kv[0], s); s = fmaf(q8[c][1], kv[1], s);
        s = fmaf(q8[c][2], kv[2], s); s = fmaf(q8[c][3], kv[3], s);
      }
      s = s * qsc * ansc[a] + bias_s[(ti - (a >> 2) + 15) * 19 + (tj - (a & 3) + 3)];
      mx = fmaxf(mx, s);
    }
    f4 o8[8] = {};
    float rs = 0.f;
#pragma unroll 1
    for (int a = 0; a < 64; a++) {
      float s = 0.f;
#pragma unroll
      for (int c = 0; c < 8; c++) {
        f4 kv = *(const f4*)(&a_s[a][c * 4]);
        s = fmaf(q8[c][0], kv[0], s); s = fmaf(q8[c][1], kv[1], s);
        s = fmaf(q8[c][2], kv[2], s); s = fmaf(q8[c][3], kv[3], s);
      }
      s = s * qsc * ansc[a] + bias_s[(ti - (a >> 2) + 15) * 19 + (tj - (a & 3) + 3)];
      const float p = __expf(s - mx);
      rs += p;
#pragma unroll
      for (int c = 0; c < 8; c++) {
        f4 tv = *(const f4*)(&t_s[a][c * 4]);
        o8[c] += tv * p;
      }
    }
    const float inv = 1.f / rs;
    float* op = outp + (rowbase + ti * 64 + tj) * 256 + 128 + head * 32;
#pragma unroll
    for (int c = 0; c < 8; c++) {
      f4 v = o8[c] * inv;
      *(f4*)(op + c * 4) = v;
    }
  }
}

// ---------------------------------------------------------------- launch
extern "C" void kernel_launch(void* const* d_in, const int* in_sizes, int n_in,
                              void* d_out, int out_size, void* d_ws, size_t ws_size,
                              hipStream_t stream) {
  (void)in_sizes; (void)n_in; (void)out_size;
  const float* x        = (const float*)d_in[0];
  const float* w_qkv    = (const float*)d_in[1];
  const float* b_qkv    = (const float*)d_in[2];
  const float* w_anchor = (const float*)d_in[3];
  const float* b_anchor = (const float*)d_in[4];
  const float* ls_w     = (const float*)d_in[5];
  const float* cw1_w    = (const float*)d_in[6];
  const float* cb1_w    = (const float*)d_in[7];
  const float* cw2_w    = (const float*)d_in[8];
  const float* ls_s1    = (const float*)d_in[9];
  const float* cw1_s1   = (const float*)d_in[10];
  const float* cb1_s1   = (const float*)d_in[11];
  const float* cw2_s1   = (const float*)d_in[12];
  const float* ls_s2    = (const float*)d_in[13];
  const float* cw1_s2   = (const float*)d_in[14];
  const float* cb1_s2   = (const float*)d_in[15];
  const float* cw2_s2   = (const float*)d_in[16];
  const float* w_proj   = (const float*)d_in[17];
  const float* b_proj   = (const float*)d_in[18];
  float* out = (float*)d_out;

  // ---- adaptive chunking over batch: fixed ~6.2 MB + NB*(6.3 MB qkv-half + 128 KB tbuf)
  const size_t fixed_bytes =
      (size_t)4096 * 256 * 4 +     // pooled
      (size_t)4096 * 128 * 4 +     // anch
      (size_t)961 * 16 + (size_t)1501 * 16 * 2 +
      32 * 256;                     // slack
  int NB = 16;
  while (NB > 1) {
    size_t need = fixed_bytes + (size_t)NB * (4096u * 384u * 4u + 16u * 2048u * 4u);
    if (need <= ws_size) break;
    NB >>= 1;
  }
  const int nchunks = 16 / NB;

  char* ws = (char*)d_ws;
  size_t off = 0;
  auto take = [&](size_t bytes) {
    char* p = ws + off;
    off += (bytes + 255) & ~(size_t)255;
    return p;
  };
  float* pooled = (float*)take((size_t)4096 * 256 * 4);
  float* anch   = (float*)take((size_t)4096 * 128 * 4);
  float* sbt_w  = (float*)take((size_t)961 * 16);
  float* sbt_s1 = (float*)take((size_t)1501 * 16);
  float* sbt_s2 = (float*)take((size_t)1501 * 16);
  float* tbuf   = (float*)take((size_t)NB * 16 * 2048 * 4);
  float* qkvh   = (float*)take((size_t)NB * 4096 * 384 * 4);

  // ---- one-time prep
  k_cpb<<<961, 64, 0, stream>>>(cw1_w, cb1_w, cw2_w, sbt_w, 31, 1.f / 15.f, 1.f / 15.f, -15, -15);
  k_cpb<<<1501, 64, 0, stream>>>(cw1_s1, cb1_s1, cw2_s1, sbt_s1, 19, 1.f / 39.f, 1.f / 9.f, -39, -9);
  k_cpb<<<1501, 64, 0, stream>>>(cw1_s2, cb1_s2, cw2_s2, sbt_s2, 19, 1.f / 39.f, 1.f / 9.f, -39, -9);
  k_pool<<<4096, 256, 0, stream>>>(x, pooled);
  k_gemm<<<(4096 / 64) * 2, 256, 0, stream>>>(pooled, w_anchor, b_anchor, anch, 4096, 128, 256, 128);

  // ---- chunked over batch
  const int M = NB * 4096;
  const int gemm_blocks = (M / 64) * 6;  // ntg = 384/64
  for (int c = 0; c < nchunks; c++) {
    const float* xc = x + (size_t)c * NB * 4096 * 256;
    float* outc = out + (size_t)c * NB * 4096 * 256;
    const float* anchc = anch + (size_t)c * NB * 256 * 128;
    // window half (qkv channels 0..383)
    k_gemm<<<gemm_blocks, 256, 0, stream>>>(xc, w_qkv, b_qkv, qkvh, M, 384, 256, 768);
    k_win_attn<<<NB * 64, 256, 0, stream>>>(qkvh, sbt_w, ls_w, outc);
    // stripe half (qkv channels 384..767) overwrites qkvh
    k_gemm<<<gemm_blocks, 256, 0, stream>>>(xc, w_qkv + 384, b_qkv + 384, qkvh, M, 384, 256, 768);
    k_stripe1<<<NB * 16, 256, 0, stream>>>(qkvh, anchc, sbt_s1, ls_s1, tbuf);
    k_stripe2<<<NB * 16, 256, 0, stream>>>(qkvh, anchc, tbuf, sbt_s2, ls_s2, outc);
  }
  // ---- final projection, in-place on out
  k_proj<<<4096, 256, 0, stream>>>(w_proj, b_proj, out);
}

// Round 5
// 1220.779 us; speedup vs baseline: 1.1545x; 1.1545x over previous
//
#include <hip/hip_runtime.h>
#include <math.h>

typedef float f4 __attribute__((ext_vector_type(4)));

#define LOGIT_MAX_F 4.605170185988092f

// ---------------------------------------------------------------- CPB tables
__global__ __launch_bounds__(64) void k_cpb(const float* __restrict__ w1,
                                            const float* __restrict__ b1,
                                            const float* __restrict__ w2,
                                            float* __restrict__ sbt,
                                            int n_cw, float inv_p0, float inv_p1,
                                            int ts_n0, int ts_n1) {
  int row = blockIdx.x;
  int lane = threadIdx.x;
  int ih = row / n_cw, iw = row % n_cw;
  float v0 = (float)(ts_n0 + ih) * inv_p0 * 8.0f;
  float v1 = (float)(ts_n1 + iw) * inv_p1 * 8.0f;
  v0 = (v0 >= 0.f ? 1.f : -1.f) * log2f(fabsf(v0) + 1.f) * (1.f / 3.f);
  v1 = (v1 >= 0.f ? 1.f : -1.f) * log2f(fabsf(v1) + 1.f) * (1.f / 3.f);
  float a0 = 0.f, a1 = 0.f, a2 = 0.f, a3 = 0.f;
  for (int j = lane; j < 512; j += 64) {
    float h = v0 * w1[j] + v1 * w1[512 + j] + b1[j];
    h = fmaxf(h, 0.f);
    a0 += h * w2[j * 4 + 0];
    a1 += h * w2[j * 4 + 1];
    a2 += h * w2[j * 4 + 2];
    a3 += h * w2[j * 4 + 3];
  }
#pragma unroll
  for (int off = 32; off > 0; off >>= 1) {
    a0 += __shfl_down(a0, off);
    a1 += __shfl_down(a1, off);
    a2 += __shfl_down(a2, off);
    a3 += __shfl_down(a3, off);
  }
  if (lane == 0) {
    sbt[row * 4 + 0] = 16.f / (1.f + expf(-a0));
    sbt[row * 4 + 1] = 16.f / (1.f + expf(-a1));
    sbt[row * 4 + 2] = 16.f / (1.f + expf(-a2));
    sbt[row * 4 + 3] = 16.f / (1.f + expf(-a3));
  }
}

// ---------------------------------------------------------------- 4x4 mean pool
__global__ __launch_bounds__(256) void k_pool(const float* __restrict__ x,
                                              float* __restrict__ pooled) {
  int blk = blockIdx.x;            // (b, gi, gj)
  int c = threadIdx.x;
  int b = blk >> 8, gi = (blk >> 4) & 15, gj = blk & 15;
  const float* xp = x + (size_t)b * 4096 * 256 + c;
  float s = 0.f;
#pragma unroll
  for (int di = 0; di < 4; di++)
#pragma unroll
    for (int dj = 0; dj < 4; dj++)
      s += xp[(size_t)((gi * 4 + di) * 64 + gj * 4 + dj) * 256];
  pooled[(size_t)blk * 256 + c] = s * 0.0625f;
}

// ---------------------------------------------------------------- f32 GEMM 64-tile (small)
__global__ __launch_bounds__(256) void k_gemm(const float* __restrict__ A,
                                              const float* __restrict__ W,
                                              const float* __restrict__ bias,
                                              float* __restrict__ C,
                                              int M, int N, int K, int ldw) {
  __shared__ float a_s[16][64];
  __shared__ float w_s[16][64];
  const int ntg = N >> 6;
  const int mb = blockIdx.x / ntg, nb = blockIdx.x % ntg;
  const int m0 = mb << 6, n0 = nb << 6;
  const int tid = threadIdx.x;
  const int tx = tid & 15, ty = tid >> 4;
  const int ar = tid >> 2, ac4 = (tid & 3) << 2;
  const int wk = tid >> 4, wc4 = (tid & 15) << 2;
  float acc[4][4] = {};
  for (int k0 = 0; k0 < K; k0 += 16) {
    f4 av = *(const f4*)(A + (size_t)(m0 + ar) * K + k0 + ac4);
    f4 wv = *(const f4*)(W + (size_t)(k0 + wk) * ldw + n0 + wc4);
    __syncthreads();
    a_s[ac4 + 0][ar] = av[0];
    a_s[ac4 + 1][ar] = av[1];
    a_s[ac4 + 2][ar] = av[2];
    a_s[ac4 + 3][ar] = av[3];
    *(f4*)(&w_s[wk][wc4]) = wv;
    __syncthreads();
#pragma unroll
    for (int kk = 0; kk < 16; kk++) {
      f4 a4 = *(const f4*)(&a_s[kk][ty << 2]);
      f4 w4 = *(const f4*)(&w_s[kk][tx << 2]);
#pragma unroll
      for (int i = 0; i < 4; i++)
#pragma unroll
        for (int j = 0; j < 4; j++)
          acc[i][j] = fmaf(a4[i], w4[j], acc[i][j]);
    }
  }
#pragma unroll
  for (int i = 0; i < 4; i++) {
    const int row = m0 + (ty << 2) + i;
#pragma unroll
    for (int j = 0; j < 4; j++) {
      const int col = n0 + (tx << 2) + j;
      C[(size_t)row * N + col] = acc[i][j] + bias[col];
    }
  }
}

// ---------------------------------------------------------------- f32 GEMM 128-tile
// C[M,N] = A[M,K(=row stride)] @ W[K, ld=ldw] + bias; M%128==0, N%128==0, K%16==0
// In-place safe when C==A and N==K (reads of a block's rows all precede its writes).
__global__ __launch_bounds__(256) void k_gemm128(const float* __restrict__ A,
                                                 const float* __restrict__ W,
                                                 const float* __restrict__ bias,
                                                 float* __restrict__ C,
                                                 int M, int N, int K, int ldw) {
  __shared__ float a_s[16][128];   // [k][m] (transposed on store)
  __shared__ float w_s[16][128];   // [k][n]
  const int ntg = N >> 7;
  const int mb = blockIdx.x / ntg, nb = blockIdx.x % ntg;
  const int m0 = mb << 7, n0 = nb << 7;
  const int tid = threadIdx.x;
  const int tx = tid & 15, ty = tid >> 4;
  const int ar = tid >> 1, ac = (tid & 1) << 3;     // A row 0..127, col-seg 0/8
  const int wk = tid >> 4, wc = (tid & 15) << 3;    // W k-row 0..15, col-seg*8
  float acc[8][8] = {};
  for (int k0 = 0; k0 < K; k0 += 16) {
    const float* Ap = A + (size_t)(m0 + ar) * K + k0 + ac;
    f4 av0 = *(const f4*)(Ap);
    f4 av1 = *(const f4*)(Ap + 4);
    const float* Wp = W + (size_t)(k0 + wk) * ldw + n0 + wc;
    f4 wv0 = *(const f4*)(Wp);
    f4 wv1 = *(const f4*)(Wp + 4);
    __syncthreads();
#pragma unroll
    for (int i = 0; i < 4; i++) {
      a_s[ac + i][ar] = av0[i];
      a_s[ac + 4 + i][ar] = av1[i];
    }
    *(f4*)(&w_s[wk][wc]) = wv0;
    *(f4*)(&w_s[wk][wc + 4]) = wv1;
    __syncthreads();
#pragma unroll
    for (int kk = 0; kk < 16; kk++) {
      f4 a0 = *(const f4*)(&a_s[kk][ty << 3]);
      f4 a1 = *(const f4*)(&a_s[kk][(ty << 3) + 4]);
      f4 w0 = *(const f4*)(&w_s[kk][tx << 3]);
      f4 w1 = *(const f4*)(&w_s[kk][(tx << 3) + 4]);
      float a8[8] = {a0[0], a0[1], a0[2], a0[3], a1[0], a1[1], a1[2], a1[3]};
      float w8[8] = {w0[0], w0[1], w0[2], w0[3], w1[0], w1[1], w1[2], w1[3]};
#pragma unroll
      for (int i = 0; i < 8; i++)
#pragma unroll
        for (int j = 0; j < 8; j++)
          acc[i][j] = fmaf(a8[i], w8[j], acc[i][j]);
    }
  }
  f4 bv0 = *(const f4*)(bias + n0 + (tx << 3));
  f4 bv1 = *(const f4*)(bias + n0 + (tx << 3) + 4);
#pragma unroll
  for (int i = 0; i < 8; i++) {
    const int row = m0 + (ty << 3) + i;
    f4 o0 = {acc[i][0] + bv0[0], acc[i][1] + bv0[1], acc[i][2] + bv0[2], acc[i][3] + bv0[3]};
    f4 o1 = {acc[i][4] + bv1[0], acc[i][5] + bv1[1], acc[i][6] + bv1[2], acc[i][7] + bv1[3]};
    *(f4*)(C + (size_t)row * N + n0 + (tx << 3)) = o0;
    *(f4*)(C + (size_t)row * N + n0 + (tx << 3) + 4) = o1;
  }
}

// ---------------------------------------------------------------- window attention
// qkvw rows stride 384 (q 0..127, k 128..255, v 256..383), chunk-local
// single-pass chunked online softmax; K staged in LDS, V broadcast from global
__global__ __launch_bounds__(256) void k_win_attn(const float* __restrict__ qkvw,
                                                  const float* __restrict__ sbt,
                                                  const float* __restrict__ ls,
                                                  float* __restrict__ outp) {
  __shared__ float k_s[256][32];
  __shared__ float kinv[256];
  __shared__ float bias_s[961];
  const int head = blockIdx.x & 3, win = blockIdx.x >> 2;
  const int b = win >> 4, wh = (win >> 2) & 3, ww = win & 3;
  const size_t rowbase = (size_t)b * 4096 + wh * 1024 + ww * 16;
  const int tid = threadIdx.x;
  const float escale = __expf(fminf(ls[head], LOGIT_MAX_F));
  {  // stage K row `tid` + inv-norm
    const float* kp = qkvw + (rowbase + (tid >> 4) * 64 + (tid & 15)) * 384 + 128 + head * 32;
    float ss = 0.f;
#pragma unroll
    for (int c = 0; c < 8; c++) {
      f4 kv = *(const f4*)(kp + c * 4);
      *(f4*)(&k_s[tid][c * 4]) = kv;
      ss += kv[0] * kv[0] + kv[1] * kv[1] + kv[2] * kv[2] + kv[3] * kv[3];
    }
    kinv[tid] = 1.f / fmaxf(sqrtf(ss), 1e-12f);
  }
  for (int i = tid; i < 961; i += 256) bias_s[i] = sbt[i * 4 + head];
  __syncthreads();

  const int qi = tid >> 4, qj = tid & 15;
  const float* qp = qkvw + (rowbase + qi * 64 + qj) * 384 + head * 32;
  f4 q8[8];
  float qss = 0.f;
#pragma unroll
  for (int c = 0; c < 8; c++) {
    q8[c] = *(const f4*)(qp + c * 4);
    qss += q8[c][0] * q8[c][0] + q8[c][1] * q8[c][1] + q8[c][2] * q8[c][2] + q8[c][3] * q8[c][3];
  }
  const float qsc = escale / fmaxf(sqrtf(qss), 1e-12f);

  float mx = -1e30f, rs = 0.f;
  f4 o8[8] = {};
#pragma unroll 1
  for (int ki = 0; ki < 16; ki++) {   // chunk = window-row of 16 keys
    const int bbase = (qi - ki + 15) * 31 + qj + 15;
    float s16[16];
    float cmx = -1e30f;
#pragma unroll
    for (int kj = 0; kj < 16; kj++) {
      const int key = ki * 16 + kj;
      float s = 0.f;
#pragma unroll
      for (int c = 0; c < 8; c++) {
        f4 kv = *(const f4*)(&k_s[key][c * 4]);
        s = fmaf(q8[c][0], kv[0], s); s = fmaf(q8[c][1], kv[1], s);
        s = fmaf(q8[c][2], kv[2], s); s = fmaf(q8[c][3], kv[3], s);
      }
      s = s * qsc * kinv[key] + bias_s[bbase - kj];
      s16[kj] = s;
      cmx = fmaxf(cmx, s);
    }
    const float nmx = fmaxf(mx, cmx);
    const float alpha = __expf(mx - nmx);
    rs *= alpha;
#pragma unroll
    for (int c = 0; c < 8; c++) o8[c] *= alpha;
    mx = nmx;
#pragma unroll
    for (int kj = 0; kj < 16; kj++) {
      const float p = __expf(s16[kj] - mx);
      rs += p;
      const float* vp = qkvw + (rowbase + ki * 64 + kj) * 384 + 256 + head * 32;
#pragma unroll
      for (int c = 0; c < 8; c++) {
        f4 vv = *(const f4*)(vp + c * 4);
        o8[c] += vv * p;
      }
    }
  }
  const float inv = 1.f / rs;
  float* op = outp + (rowbase + qi * 64 + qj) * 256 + head * 32;
#pragma unroll
  for (int c = 0; c < 8; c++) {
    f4 v = o8[c] * inv;
    *(f4*)(op + c * 4) = v;
  }
}

// ---------------------------------------------------------------- stripe stage 1
// anchors (64 q) attend to 1024 tokens; block=(b,wj,head); 4-way key split, online
__global__ __launch_bounds__(256) void k_stripe1(const float* __restrict__ qkvs,
                                                 const float* __restrict__ anch,
                                                 const float* __restrict__ sbt,
                                                 const float* __restrict__ ls,
                                                 float* __restrict__ tbuf) {
  __shared__ float kinv_s[1024];
  __shared__ float ansc[64];
  __shared__ float bias_s[1501];
  __shared__ float mxred[64][4];
  __shared__ float rsred[64][4];
  __shared__ float opart[64][4][33];
  const int head = blockIdx.x & 3, sb = blockIdx.x >> 2;
  const int b = sb >> 2, wj = sb & 3;
  const size_t rowbase = (size_t)b * 4096 + wj * 16;
  const size_t abase = (size_t)b * 256 + wj * 4;
  const int tid = threadIdx.x;
  const int q = tid & 63, sl = tid >> 6;
  const float escale = __expf(fminf(ls[head], LOGIT_MAX_F));
  for (int tt = tid; tt < 1024; tt += 256) {  // precompute key inv-norms
    const float* kp = qkvs + (rowbase + (tt >> 4) * 64 + (tt & 15)) * 384 + 128 + head * 32;
    float ss = 0.f;
#pragma unroll
    for (int c = 0; c < 8; c++) {
      f4 kv = *(const f4*)(kp + c * 4);
      ss += kv[0] * kv[0] + kv[1] * kv[1] + kv[2] * kv[2] + kv[3] * kv[3];
    }
    kinv_s[tt] = 1.f / fmaxf(sqrtf(ss), 1e-12f);
  }
  if (tid < 64) {
    const float* ap = anch + (abase + (tid >> 2) * 16 + (tid & 3)) * 128 + head * 32;
    float ss = 0.f;
#pragma unroll
    for (int c = 0; c < 8; c++) {
      f4 v = *(const f4*)(ap + c * 4);
      ss += v[0] * v[0] + v[1] * v[1] + v[2] * v[2] + v[3] * v[3];
    }
    ansc[tid] = 1.f / fmaxf(sqrtf(ss), 1e-12f);
  }
  for (int i = tid; i < 1501; i += 256) bias_s[i] = sbt[i * 4 + head];
  __syncthreads();

  const float* qp = anch + (abase + (q >> 2) * 16 + (q & 3)) * 128 + head * 32;
  f4 q8[8];
#pragma unroll
  for (int c = 0; c < 8; c++) q8[c] = *(const f4*)(qp + c * 4);
  const float qsc = escale * ansc[q];
  const int ah = q >> 2, aw = q & 3;

  float mx = -1e30f, rs = 0.f;
  f4 o8[8] = {};
#pragma unroll 1
  for (int cc = 0; cc < 16; cc++) {          // chunk = one stripe row ti
    const int ti = sl * 16 + cc;
    const int bb = (ah - ti + 63) * 19 + aw + 15;
    const float* rowp = qkvs + (rowbase + ti * 64) * 384 + head * 32;
    float s16[16];
    float cmx = -1e30f;
#pragma unroll
    for (int tj = 0; tj < 16; tj++) {
      const float* kp = rowp + tj * 384 + 128;
      float s = 0.f;
#pragma unroll
      for (int c = 0; c < 8; c++) {
        f4 kv = *(const f4*)(kp + c * 4);
        s = fmaf(q8[c][0], kv[0], s); s = fmaf(q8[c][1], kv[1], s);
        s = fmaf(q8[c][2], kv[2], s); s = fmaf(q8[c][3], kv[3], s);
      }
      s = s * qsc * kinv_s[ti * 16 + tj] + bias_s[bb - tj];
      s16[tj] = s;
      cmx = fmaxf(cmx, s);
    }
    const float nmx = fmaxf(mx, cmx);
    const float alpha = __expf(mx - nmx);
    rs *= alpha;
#pragma unroll
    for (int c = 0; c < 8; c++) o8[c] *= alpha;
    mx = nmx;
#pragma unroll
    for (int tj = 0; tj < 16; tj++) {
      const float p = __expf(s16[tj] - mx);
      rs += p;
      const float* vp = rowp + tj * 384 + 256;
#pragma unroll
      for (int c = 0; c < 8; c++) {
        f4 vv = *(const f4*)(vp + c * 4);
        o8[c] += vv * p;
      }
    }
  }
  mxred[q][sl] = mx;
  __syncthreads();
  const float mxg = fmaxf(fmaxf(mxred[q][0], mxred[q][1]), fmaxf(mxred[q][2], mxred[q][3]));
  const float w = __expf(mx - mxg);
  rsred[q][sl] = rs * w;
#pragma unroll
  for (int c = 0; c < 8; c++) {
    opart[q][sl][c * 4 + 0] = o8[c][0] * w;
    opart[q][sl][c * 4 + 1] = o8[c][1] * w;
    opart[q][sl][c * 4 + 2] = o8[c][2] * w;
    opart[q][sl][c * 4 + 3] = o8[c][3] * w;
  }
  __syncthreads();
  {
    const int q2 = tid >> 2, cg = (tid & 3) << 3;
    const float inv = 1.f / (rsred[q2][0] + rsred[q2][1] + rsred[q2][2] + rsred[q2][3]);
    float* tp = tbuf + (size_t)blockIdx.x * 2048 + q2 * 32 + cg;
#pragma unroll
    for (int i = 0; i < 8; i++) {
      const int c = cg + i;
      tp[i] = (opart[q2][0][c] + opart[q2][1][c] + opart[q2][2][c] + opart[q2][3][c]) * inv;
    }
  }
}

// ---------------------------------------------------------------- stripe stage 2
// 1024 tokens attend to 64 anchors, values = t; scores kept in registers
__global__ __launch_bounds__(256) void k_stripe2(const float* __restrict__ qkvs,
                                                 const float* __restrict__ anch,
                                                 const float* __restrict__ tbuf,
                                                 const float* __restrict__ sbt,
                                                 const float* __restrict__ ls,
                                                 float* __restrict__ outp) {
  __shared__ float a_s[64][32];
  __shared__ float t_s[64][32];
  __shared__ float ansc[64];
  __shared__ float bias_s[1501];
  const int head = blockIdx.x & 3, sb = blockIdx.x >> 2;
  const int b = sb >> 2, wj = sb & 3;
  const size_t rowbase = (size_t)b * 4096 + wj * 16;
  const size_t abase = (size_t)b * 256 + wj * 4;
  const int tid = threadIdx.x;
  const float escale = __expf(fminf(ls[head], LOGIT_MAX_F));
  if (tid < 64) {
    const float* ap = anch + (abase + (tid >> 2) * 16 + (tid & 3)) * 128 + head * 32;
    const float* tp = tbuf + (size_t)blockIdx.x * 2048 + tid * 32;
    float ss = 0.f;
#pragma unroll
    for (int c = 0; c < 8; c++) {
      f4 v = *(const f4*)(ap + c * 4);
      *(f4*)(&a_s[tid][c * 4]) = v;
      ss += v[0] * v[0] + v[1] * v[1] + v[2] * v[2] + v[3] * v[3];
      *(f4*)(&t_s[tid][c * 4]) = *(const f4*)(tp + c * 4);
    }
    ansc[tid] = 1.f / fmaxf(sqrtf(ss), 1e-12f);
  }
  for (int i = tid; i < 1501; i += 256) bias_s[i] = sbt[i * 4 + head];
  __syncthreads();

#pragma unroll 1
  for (int rep = 0; rep < 4; rep++) {
    const int qt = rep * 256 + tid;
    const int ti = qt >> 4, tj = qt & 15;
    const float* qp = qkvs + (rowbase + ti * 64 + tj) * 384 + head * 32;
    f4 q8[8];
    float qss = 0.f;
#pragma unroll
    for (int c = 0; c < 8; c++) {
      q8[c] = *(const f4*)(qp + c * 4);
      qss += q8[c][0] * q8[c][0] + q8[c][1] * q8[c][1] + q8[c][2] * q8[c][2] + q8[c][3] * q8[c][3];
    }
    const float qsc = escale / fmaxf(sqrtf(qss), 1e-12f);
    float sarr[64];
    float mx = -1e30f;
#pragma unroll 1
    for (int a = 0; a < 64; a++) {
      float s = 0.f;
#pragma unroll
      for (int c = 0; c < 8; c++) {
        f4 kv = *(const f4*)(&a_s[a][c * 4]);
        s = fmaf(q8[c][0], kv[0], s); s = fmaf(q8[c][1], kv[1], s);
        s = fmaf(q8[c][2], kv[2], s); s = fmaf(q8[c][3], kv[3], s);
      }
      s = s * qsc * ansc[a] + bias_s[(ti - (a >> 2) + 15) * 19 + (tj - (a & 3) + 3)];
      sarr[a] = s;
      mx = fmaxf(mx, s);
    }
    f4 o8[8] = {};
    float rs = 0.f;
#pragma unroll 1
    for (int a = 0; a < 64; a++) {
      const float p = __expf(sarr[a] - mx);
      rs += p;
#pragma unroll
      for (int c = 0; c < 8; c++) {
        f4 tv = *(const f4*)(&t_s[a][c * 4]);
        o8[c] += tv * p;
      }
    }
    const float inv = 1.f / rs;
    float* op = outp + (rowbase + ti * 64 + tj) * 256 + 128 + head * 32;
#pragma unroll
    for (int c = 0; c < 8; c++) {
      f4 v = o8[c] * inv;
      *(f4*)(op + c * 4) = v;
    }
  }
}

// ---------------------------------------------------------------- launch
extern "C" void kernel_launch(void* const* d_in, const int* in_sizes, int n_in,
                              void* d_out, int out_size, void* d_ws, size_t ws_size,
                              hipStream_t stream) {
  (void)in_sizes; (void)n_in; (void)out_size;
  const float* x        = (const float*)d_in[0];
  const float* w_qkv    = (const float*)d_in[1];
  const float* b_qkv    = (const float*)d_in[2];
  const float* w_anchor = (const float*)d_in[3];
  const float* b_anchor = (const float*)d_in[4];
  const float* ls_w     = (const float*)d_in[5];
  const float* cw1_w    = (const float*)d_in[6];
  const float* cb1_w    = (const float*)d_in[7];
  const float* cw2_w    = (const float*)d_in[8];
  const float* ls_s1    = (const float*)d_in[9];
  const float* cw1_s1   = (const float*)d_in[10];
  const float* cb1_s1   = (const float*)d_in[11];
  const float* cw2_s1   = (const float*)d_in[12];
  const float* ls_s2    = (const float*)d_in[13];
  const float* cw1_s2   = (const float*)d_in[14];
  const float* cb1_s2   = (const float*)d_in[15];
  const float* cw2_s2   = (const float*)d_in[16];
  const float* w_proj   = (const float*)d_in[17];
  const float* b_proj   = (const float*)d_in[18];
  float* out = (float*)d_out;

  // ---- adaptive chunking over batch
  const size_t fixed_bytes =
      (size_t)4096 * 256 * 4 +     // pooled
      (size_t)4096 * 128 * 4 +     // anch
      (size_t)961 * 16 + (size_t)1501 * 16 * 2 +
      32 * 256;                     // slack
  int NB = 16;
  while (NB > 1) {
    size_t need = fixed_bytes + (size_t)NB * (4096u * 384u * 4u + 16u * 2048u * 4u);
    if (need <= ws_size) break;
    NB >>= 1;
  }
  const int nchunks = 16 / NB;

  char* ws = (char*)d_ws;
  size_t off = 0;
  auto take = [&](size_t bytes) {
    char* p = ws + off;
    off += (bytes + 255) & ~(size_t)255;
    return p;
  };
  float* pooled = (float*)take((size_t)4096 * 256 * 4);
  float* anch   = (float*)take((size_t)4096 * 128 * 4);
  float* sbt_w  = (float*)take((size_t)961 * 16);
  float* sbt_s1 = (float*)take((size_t)1501 * 16);
  float* sbt_s2 = (float*)take((size_t)1501 * 16);
  float* tbuf   = (float*)take((size_t)NB * 16 * 2048 * 4);
  float* qkvh   = (float*)take((size_t)NB * 4096 * 384 * 4);

  // ---- one-time prep
  k_cpb<<<961, 64, 0, stream>>>(cw1_w, cb1_w, cw2_w, sbt_w, 31, 1.f / 15.f, 1.f / 15.f, -15, -15);
  k_cpb<<<1501, 64, 0, stream>>>(cw1_s1, cb1_s1, cw2_s1, sbt_s1, 19, 1.f / 39.f, 1.f / 9.f, -39, -9);
  k_cpb<<<1501, 64, 0, stream>>>(cw1_s2, cb1_s2, cw2_s2, sbt_s2, 19, 1.f / 39.f, 1.f / 9.f, -39, -9);
  k_pool<<<4096, 256, 0, stream>>>(x, pooled);
  k_gemm<<<(4096 / 64) * 2, 256, 0, stream>>>(pooled, w_anchor, b_anchor, anch, 4096, 128, 256, 128);

  // ---- chunked over batch
  const int M = NB * 4096;
  const int gemm_blocks = (M / 128) * 3;  // ntg = 384/128
  for (int c = 0; c < nchunks; c++) {
    const float* xc = x + (size_t)c * NB * 4096 * 256;
    float* outc = out + (size_t)c * NB * 4096 * 256;
    const float* anchc = anch + (size_t)c * NB * 256 * 128;
    // window half (qkv channels 0..383)
    k_gemm128<<<gemm_blocks, 256, 0, stream>>>(xc, w_qkv, b_qkv, qkvh, M, 384, 256, 768);
    k_win_attn<<<NB * 64, 256, 0, stream>>>(qkvh, sbt_w, ls_w, outc);
    // stripe half (qkv channels 384..767) overwrites qkvh
    k_gemm128<<<gemm_blocks, 256, 0, stream>>>(xc, w_qkv + 384, b_qkv + 384, qkvh, M, 384, 256, 768);
    k_stripe1<<<NB * 16, 256, 0, stream>>>(qkvh, anchc, sbt_s1, ls_s1, tbuf);
    k_stripe2<<<NB * 16, 256, 0, stream>>>(qkvh, anchc, tbuf, sbt_s2, ls_s2, outc);
  }
  // ---- final projection, in-place on out (block reads own rows before writing)
  k_gemm128<<<(65536 / 128) * 2, 256, 0, stream>>>(out, w_proj, b_proj, out, 65536, 256, 256, 256);
}